// Round 4
// baseline (614.859 us; speedup 1.0000x reference)
//
#include <hip/hip_runtime.h>
#include <math.h>

// Problem: B=4, C=256, N=H*W=4096, G=32 groups (8 ch/group).
// ALL inputs and the output are FLOAT32 (reference is jnp.float32).
// Internally we stage h/q/k/v/w as bf16 for MFMA; accumulate fp32.
// out = x + nin3( attn( nin0/1/2( groupnorm(x) ) ) )
//
// Buffer plan:
//   d_out (16 MB f32) : first 8 MB doubles as h_t [B][N][C] bf16 scratch during
//                       the QKV gemms (fully dead before attn_k writes output)
//   ws: q_t [B][N][C] bf16   8 MB
//       k_t [B][N][C] bf16   8 MB
//       v   [B][C][N] bf16   8 MB
//       wT  4x[256][256] bf16 512 KB
//       stats [128][2] f32   1 KB      total ~24.6 MB

typedef short short8    __attribute__((ext_vector_type(8)));
typedef ushort ushort8  __attribute__((ext_vector_type(8)));
typedef float f32x4     __attribute__((ext_vector_type(4)));

#define BB 4
#define CCH 256
#define NSP 4096

__device__ __forceinline__ ushort f2b(float f){
  unsigned int u; __builtin_memcpy(&u, &f, 4);
  u += 0x7fffu + ((u >> 16) & 1u);   // RTNE
  return (ushort)(u >> 16);
}

// ---------------- GroupNorm stats: one block per (b,g); slice contiguous f32 ----
__global__ __launch_bounds__(256) void gn_stats_k(const float* __restrict__ x,
                                                  float* __restrict__ stats){
  const int bg = blockIdx.x;                       // b*32+g ; slice = 32768 f32
  const f32x4* p = (const f32x4*)(x + (size_t)bg * 32768);
  float s = 0.f, s2 = 0.f;
  for (int i = threadIdx.x; i < 8192; i += 256){
    f32x4 v = p[i];
    #pragma unroll
    for (int j = 0; j < 4; j++){ s += v[j]; s2 += v[j]*v[j]; }
  }
  #pragma unroll
  for (int off = 32; off >= 1; off >>= 1){
    s  += __shfl_down(s,  off, 64);
    s2 += __shfl_down(s2, off, 64);
  }
  __shared__ float red[8];
  const int w = threadIdx.x >> 6;
  if ((threadIdx.x & 63) == 0){ red[w*2] = s; red[w*2+1] = s2; }
  __syncthreads();
  if (threadIdx.x == 0){
    float S  = red[0]+red[2]+red[4]+red[6];
    float S2 = red[1]+red[3]+red[5]+red[7];
    float mean = S * (1.f/32768.f);
    float var  = fmaxf(S2 * (1.f/32768.f) - mean*mean, 0.f);
    stats[bg*2]   = mean;
    stats[bg*2+1] = rsqrtf(var + 1e-6f);
  }
}

// ------- GN apply + transpose + f32->bf16: x[b][c][n] f32 -> h_t[b][n][c] bf16 --
__global__ __launch_bounds__(256) void gn_apply_k(const float* __restrict__ x,
                                                  const float* __restrict__ stats,
                                                  const float* __restrict__ gamma,
                                                  const float* __restrict__ beta,
                                                  ushort* __restrict__ h_t){
  __shared__ ushort tile[64][72];                  // [n_local][c_local], padded
  const int b = blockIdx.z, c0 = blockIdx.y*64, n0 = blockIdx.x*64;
  const int t = threadIdx.x;
  #pragma unroll
  for (int p = 0; p < 2; p++){
    const int cl = p*32 + (t >> 3);
    const int nc = (t & 7) * 8;
    const int c = c0 + cl;
    const float mean = stats[(b*32 + (c>>3))*2];
    const float rstd = stats[(b*32 + (c>>3))*2 + 1];
    const float sc = rstd * gamma[c];
    const float sh = beta[c] - mean * sc;
    const float* xr = x + ((size_t)b*CCH + c)*NSP + n0 + nc;
    f32x4 a = *(const f32x4*)xr;
    f32x4 d = *(const f32x4*)(xr + 4);
    #pragma unroll
    for (int j = 0; j < 4; j++){
      tile[nc + j][cl]     = f2b(a[j]*sc + sh);
      tile[nc + 4 + j][cl] = f2b(d[j]*sc + sh);
    }
  }
  __syncthreads();
  #pragma unroll
  for (int p = 0; p < 2; p++){
    const int nl = p*32 + (t >> 3);
    const int cc = (t & 7) * 8;
    ushort8 ov;
    #pragma unroll
    for (int j = 0; j < 8; j++) ov[j] = tile[nl][cc + j];
    *(ushort8*)(h_t + ((size_t)b*NSP + n0 + nl)*CCH + c0 + cc) = ov;
  }
}

// ------- weight transpose + cast: wT[d][c] = bf16(w[c][d]), 4 weights (f32 in) --
__global__ __launch_bounds__(256) void transpose_w4_k(const float* __restrict__ w0,
                                                      const float* __restrict__ w1,
                                                      const float* __restrict__ w2,
                                                      const float* __restrict__ w3,
                                                      ushort* __restrict__ wT){
  __shared__ ushort tile[64][72];
  const float* w = (blockIdx.y==0) ? w0 : (blockIdx.y==1) ? w1 : (blockIdx.y==2) ? w2 : w3;
  ushort* dst = wT + (size_t)blockIdx.y * 65536;
  const int tb = blockIdx.x;
  const int r0 = (tb >> 2) * 64, c0 = (tb & 3) * 64;   // r0: src row (c), c0: src col (d)
  const int t = threadIdx.x;
  #pragma unroll
  for (int p = 0; p < 2; p++){
    const int r = p*32 + (t >> 3), cc = (t & 7)*8;
    const float* wr = w + (size_t)(r0 + r)*256 + c0 + cc;
    f32x4 a = *(const f32x4*)wr;
    f32x4 d = *(const f32x4*)(wr + 4);
    #pragma unroll
    for (int j = 0; j < 4; j++){
      tile[r][cc + j]     = f2b(a[j]);
      tile[r][cc + 4 + j] = f2b(d[j]);
    }
  }
  __syncthreads();
  #pragma unroll
  for (int p = 0; p < 2; p++){
    const int r = p*32 + (t >> 3), cc = (t & 7)*8;
    ushort8 ov;
    #pragma unroll
    for (int j = 0; j < 8; j++) ov[j] = tile[cc + j][r];
    *(ushort8*)(dst + (size_t)(c0 + r)*256 + r0 + cc) = ov;
  }
}

// ------------- GEMM: D[m][n] = sum_k A[m][k]*B[n][k]; OutT[n][m] = D + biases ---
// A,B,OutT bf16; biases f32. K fixed = 256.
__global__ __launch_bounds__(256) void gemm_bt_k(const ushort* __restrict__ A,
                                                 const ushort* __restrict__ B,
                                                 ushort* __restrict__ OutT,
                                                 int M, int N,
                                                 long aStride, long bStride, long oStride,
                                                 const float* __restrict__ biasM,
                                                 const float* __restrict__ biasN){
  const int K = 256;
  const int t = threadIdx.x, w = t >> 6, lane = t & 63;
  const int li = lane & 15, quad = lane >> 4;
  const int m64 = M >> 6;
  const int tm = blockIdx.x % m64, tn = blockIdx.x / m64;
  const int batch = blockIdx.y;
  A    += (size_t)batch * aStride;
  B    += (size_t)batch * bStride;
  OutT += (size_t)batch * oStride;
  const int m0 = tm*64 + w*16;
  const int nb = tn*64;

  short8 afr[8];
  #pragma unroll
  for (int kk = 0; kk < 8; kk++)
    afr[kk] = *(const short8*)(A + (size_t)(m0 + li)*K + kk*32 + quad*8);

  #pragma unroll
  for (int nt = 0; nt < 4; nt++){
    f32x4 acc = {0.f,0.f,0.f,0.f};
    const int n = nb + nt*16 + li;
    #pragma unroll
    for (int kk = 0; kk < 8; kk++){
      short8 bfr = *(const short8*)(B + (size_t)n*K + kk*32 + quad*8);
      acc = __builtin_amdgcn_mfma_f32_16x16x32_bf16(afr[kk], bfr, acc, 0, 0, 0);
    }
    const float bn = biasN ? biasN[n] : 0.f;
    ushort ov[4];
    #pragma unroll
    for (int r = 0; r < 4; r++){
      const float bm = biasM ? biasM[m0 + quad*4 + r] : 0.f;
      ov[r] = f2b(acc[r] + bm + bn);
    }
    ushort8 dummy;
    *(ushort*)&dummy = 0; (void)dummy;
    // 8-byte store of 4 bf16
    *(uint2*)(OutT + (size_t)n*M + m0 + quad*4) = *(uint2*)ov;
  }
}

// ---------------- fused flash attention + final projection + residual ----------
// grid 256 = 4 batches * 64 q-tiles(64). 4 waves, wave w owns 16 queries.
__global__ __launch_bounds__(256) void attn_k(const ushort* __restrict__ qg,
                                              const ushort* __restrict__ kg,
                                              const ushort* __restrict__ vg,
                                              const ushort* __restrict__ w3T,
                                              const float* __restrict__ b3,
                                              const float* __restrict__ xin,
                                              float* __restrict__ out){
  __shared__ __align__(16) ushort Kt[64][264];     // [key][c]
  __shared__ __align__(16) ushort Pl[4][16][72];   // per-wave P [query][key]

  const int t = threadIdx.x, w = t >> 6, lane = t & 63;
  const int li = lane & 15, quad = lane >> 4;
  const int b = blockIdx.x >> 6;
  const int n0 = (blockIdx.x & 63) * 64;

  const ushort* kb = kg + (size_t)b*NSP*CCH;
  const ushort* vb = vg + (size_t)b*CCH*NSP;

  short8 qf[8];
  {
    const ushort* qrow = qg + ((size_t)b*NSP + n0 + w*16 + li)*CCH + quad*8;
    #pragma unroll
    for (int kk = 0; kk < 8; kk++) qf[kk] = *(const short8*)(qrow + kk*32);
  }

  f32x4 oacc[16];
  #pragma unroll
  for (int i = 0; i < 16; i++) oacc[i] = (f32x4){0.f,0.f,0.f,0.f};
  float m_i[4] = {-1e30f,-1e30f,-1e30f,-1e30f};
  float l_i[4] = {0.f,0.f,0.f,0.f};
  const float c1 = 0.0625f * 1.44269504088896f;    // C^-0.5 * log2(e)

  for (int kt = 0; kt < 64; kt++){
    const int key0 = kt * 64;
    __syncthreads();                               // Kt free for overwrite
    #pragma unroll
    for (int i = 0; i < 8; i++){                   // stage 64x256 bf16 K tile
      const int idx = t + i*256;
      const int key = idx >> 5, cc = (idx & 31) * 8;
      *(ushort8*)&Kt[key][cc] = *(const ushort8*)(kb + (size_t)(key0 + key)*CCH + cc);
    }
    __syncthreads();                               // Kt staged

    f32x4 sacc[4];
    #pragma unroll
    for (int nt = 0; nt < 4; nt++) sacc[nt] = (f32x4){0.f,0.f,0.f,0.f};
    #pragma unroll
    for (int nt = 0; nt < 4; nt++){
      #pragma unroll
      for (int kk = 0; kk < 8; kk++){
        short8 bfr = *(const short8*)&Kt[nt*16 + li][kk*32 + quad*8];
        sacc[nt] = __builtin_amdgcn_mfma_f32_16x16x32_bf16(qf[kk], bfr, sacc[nt], 0, 0, 0);
      }
    }

    // online softmax (exp2 domain). Lane holds rows quad*4+r, cols nt*16+li.
    float rmax[4];
    #pragma unroll
    for (int r = 0; r < 4; r++)
      rmax[r] = fmaxf(fmaxf(sacc[0][r], sacc[1][r]), fmaxf(sacc[2][r], sacc[3][r]));
    #pragma unroll
    for (int off = 1; off < 16; off <<= 1){
      #pragma unroll
      for (int r = 0; r < 4; r++) rmax[r] = fmaxf(rmax[r], __shfl_xor(rmax[r], off, 64));
    }
    float alpha[4];
    #pragma unroll
    for (int r = 0; r < 4; r++){
      const float mc = rmax[r] * c1;
      const float mn = fmaxf(m_i[r], mc);
      alpha[r] = __builtin_amdgcn_exp2f(m_i[r] - mn);
      m_i[r] = mn;
    }
    float rsum[4] = {0.f,0.f,0.f,0.f};
    #pragma unroll
    for (int nt = 0; nt < 4; nt++){
      #pragma unroll
      for (int r = 0; r < 4; r++){
        const float pv = __builtin_amdgcn_exp2f(sacc[nt][r]*c1 - m_i[r]);
        rsum[r] += pv;
        Pl[w][quad*4 + r][nt*16 + li] = f2b(pv);
      }
    }
    #pragma unroll
    for (int off = 1; off < 16; off <<= 1){
      #pragma unroll
      for (int r = 0; r < 4; r++) rsum[r] += __shfl_xor(rsum[r], off, 64);
    }
    #pragma unroll
    for (int r = 0; r < 4; r++) l_i[r] = l_i[r]*alpha[r] + rsum[r];
    #pragma unroll
    for (int ct = 0; ct < 16; ct++){
      #pragma unroll
      for (int r = 0; r < 4; r++) oacc[ct][r] *= alpha[r];
    }

    __syncthreads();                               // Pl writes visible

    // O += P * V ; A-frag from Pl, B-frag direct from global v[c][key]
    #pragma unroll
    for (int ks = 0; ks < 2; ks++){
      short8 af = *(const short8*)&Pl[w][li][ks*32 + quad*8];
      #pragma unroll
      for (int ct = 0; ct < 16; ct++){
        short8 vf = *(const short8*)(vb + (size_t)(ct*16 + li)*NSP + key0 + ks*32 + quad*8);
        oacc[ct] = __builtin_amdgcn_mfma_f32_16x16x32_bf16(af, vf, oacc[ct], 0, 0, 0);
      }
    }
  }

  float rinv[4];
  #pragma unroll
  for (int r = 0; r < 4; r++) rinv[r] = 1.f / l_i[r];

  __syncthreads();                                  // all waves done with Kt/Pl
  ushort* Ol = &Kt[0][0] + (size_t)w*16*264;        // reuse Kt: [16][264] per wave
  #pragma unroll
  for (int ct = 0; ct < 16; ct++){
    #pragma unroll
    for (int r = 0; r < 4; r++)
      Ol[(quad*4 + r)*264 + ct*16 + li] = f2b(oacc[ct][r] * rinv[r]);
  }
  __syncthreads();                                  // Ol writes ordered

  short8 af2[8];                                    // O as A-operand (same wave)
  #pragma unroll
  for (int kk = 0; kk < 8; kk++)
    af2[kk] = *(const short8*)&Ol[li*264 + kk*32 + quad*8];

  #pragma unroll
  for (int ct = 0; ct < 16; ct++){
    f32x4 facc = {0.f,0.f,0.f,0.f};
    #pragma unroll
    for (int kk = 0; kk < 8; kk++){
      short8 wf = *(const short8*)(w3T + (size_t)(ct*16 + li)*256 + kk*32 + quad*8);
      facc = __builtin_amdgcn_mfma_f32_16x16x32_bf16(af2[kk], wf, facc, 0, 0, 0);
    }
    const int c = ct*16 + li;
    const float bias = b3[c];
    const int n = n0 + w*16 + quad*4;
    const size_t idx = ((size_t)b*CCH + c)*NSP + n;
    f32x4 xv = *(const f32x4*)(xin + idx);
    f32x4 ov;
    #pragma unroll
    for (int r = 0; r < 4; r++) ov[r] = facc[r] + bias + xv[r];
    *(f32x4*)(out + idx) = ov;
  }
}

extern "C" void kernel_launch(void* const* d_in, const int* in_sizes, int n_in,
                              void* d_out, int out_size, void* d_ws, size_t ws_size,
                              hipStream_t stream){
  const float* x     = (const float*)d_in[0];
  const float* gamma = (const float*)d_in[1];
  const float* beta  = (const float*)d_in[2];
  const float* w0    = (const float*)d_in[3];
  const float* b0    = (const float*)d_in[4];
  const float* w1    = (const float*)d_in[5];
  const float* b1    = (const float*)d_in[6];
  const float* w2    = (const float*)d_in[7];
  const float* b2    = (const float*)d_in[8];
  const float* w3    = (const float*)d_in[9];
  const float* b3    = (const float*)d_in[10];
  float* out = (float*)d_out;

  const size_t TEN = (size_t)BB * NSP * CCH;        // 4M elements
  ushort* h_t = (ushort*)d_out;                     // first 8MB of d_out as scratch
  ushort* q_t = (ushort*)d_ws;
  ushort* k_t = q_t + TEN;
  ushort* v   = k_t + TEN;
  ushort* wT  = v + TEN;                            // 4 x 65536 bf16
  float* stats = (float*)(wT + 4*65536);

  transpose_w4_k<<<dim3(16,4), 256, 0, stream>>>(w0, w1, w2, w3, wT);
  gn_stats_k<<<128, 256, 0, stream>>>(x, stats);
  gn_apply_k<<<dim3(64,4,4), 256, 0, stream>>>(x, stats, gamma, beta, h_t);

  const long HS = (long)NSP * CCH;
  // q_t[n][d] : A=w0T (M=d=256), B=h_t (N=n=4096), biasM=b0
  gemm_bt_k<<<dim3(256, BB), 256, 0, stream>>>(wT,         h_t, q_t, 256, 4096, 0, HS, HS, b0, nullptr);
  gemm_bt_k<<<dim3(256, BB), 256, 0, stream>>>(wT+65536,   h_t, k_t, 256, 4096, 0, HS, HS, b1, nullptr);
  // v[d][n] : A=h_t (M=n=4096), B=w2T (N=d=256), biasN=b2
  gemm_bt_k<<<dim3(256, BB), 256, 0, stream>>>(h_t, wT+2*65536, v, 4096, 256, HS, 0, HS, nullptr, b2);

  attn_k<<<256, 256, 0, stream>>>(q_t, k_t, v, wT + 3*65536, b3, x, out);
}

// Round 5
// 367.583 us; speedup vs baseline: 1.6727x; 1.6727x over previous
//
#include <hip/hip_runtime.h>
#include <math.h>

// B=4, C=256, N=H*W=4096, G=32. All inputs/output FLOAT32; bf16 internally.
// out = x + nin3( attn( nin0/1/2( groupnorm(x) ) ) )
//
// Pipeline:
//  1 transpose_w4   : wT[d][c] bf16
//  2 gn_stats       : mean/rstd per (b,g)
//  3 gn_apply       : h_t[b][n][c] bf16   (lives in d_out[0:8MB], dead later)
//  4 gemm_bt x3     : q_t,k_t [b][n][c];  v [b][c][n]   (ws)
//  5 attn_split     : grid 512 = (b,qtile,keyhalf); flash attn over 2048 keys;
//                     partial O bf16 -> d_out (16MB, exact fit), m/l -> ws
//  6 combine        : merge halves -> Oc[b][n][c] bf16 (reuses dead k_t)
//  7 gemm_proj      : out = x + b3 + Oc·w3   (f32, overwrites d_out)

typedef short short8    __attribute__((ext_vector_type(8)));
typedef ushort ushort8  __attribute__((ext_vector_type(8)));
typedef float f32x4     __attribute__((ext_vector_type(4)));

#define BB 4
#define CCH 256
#define NSP 4096

__device__ __forceinline__ float b2f(ushort h){
  unsigned int u = ((unsigned int)h) << 16;
  float f; __builtin_memcpy(&f, &u, 4); return f;
}
__device__ __forceinline__ ushort f2b(float f){
  unsigned int u; __builtin_memcpy(&u, &f, 4);
  u += 0x7fffu + ((u >> 16) & 1u);   // RTNE
  return (ushort)(u >> 16);
}

// ---------------- GroupNorm stats ----------------
__global__ __launch_bounds__(256) void gn_stats_k(const float* __restrict__ x,
                                                  float* __restrict__ stats){
  const int bg = blockIdx.x;
  const f32x4* p = (const f32x4*)(x + (size_t)bg * 32768);
  float s = 0.f, s2 = 0.f;
  for (int i = threadIdx.x; i < 8192; i += 256){
    f32x4 v = p[i];
    #pragma unroll
    for (int j = 0; j < 4; j++){ s += v[j]; s2 += v[j]*v[j]; }
  }
  #pragma unroll
  for (int off = 32; off >= 1; off >>= 1){
    s  += __shfl_down(s,  off, 64);
    s2 += __shfl_down(s2, off, 64);
  }
  __shared__ float red[8];
  const int w = threadIdx.x >> 6;
  if ((threadIdx.x & 63) == 0){ red[w*2] = s; red[w*2+1] = s2; }
  __syncthreads();
  if (threadIdx.x == 0){
    float S  = red[0]+red[2]+red[4]+red[6];
    float S2 = red[1]+red[3]+red[5]+red[7];
    float mean = S * (1.f/32768.f);
    float var  = fmaxf(S2 * (1.f/32768.f) - mean*mean, 0.f);
    stats[bg*2]   = mean;
    stats[bg*2+1] = rsqrtf(var + 1e-6f);
  }
}

// ------- GN apply + transpose + cast: x[b][c][n] f32 -> h_t[b][n][c] bf16 ------
__global__ __launch_bounds__(256) void gn_apply_k(const float* __restrict__ x,
                                                  const float* __restrict__ stats,
                                                  const float* __restrict__ gamma,
                                                  const float* __restrict__ beta,
                                                  ushort* __restrict__ h_t){
  __shared__ ushort tile[64][72];
  const int b = blockIdx.z, c0 = blockIdx.y*64, n0 = blockIdx.x*64;
  const int t = threadIdx.x;
  #pragma unroll
  for (int p = 0; p < 2; p++){
    const int cl = p*32 + (t >> 3);
    const int nc = (t & 7) * 8;
    const int c = c0 + cl;
    const float mean = stats[(b*32 + (c>>3))*2];
    const float rstd = stats[(b*32 + (c>>3))*2 + 1];
    const float sc = rstd * gamma[c];
    const float sh = beta[c] - mean * sc;
    const float* xr = x + ((size_t)b*CCH + c)*NSP + n0 + nc;
    f32x4 a = *(const f32x4*)xr;
    f32x4 d = *(const f32x4*)(xr + 4);
    #pragma unroll
    for (int j = 0; j < 4; j++){
      tile[nc + j][cl]     = f2b(a[j]*sc + sh);
      tile[nc + 4 + j][cl] = f2b(d[j]*sc + sh);
    }
  }
  __syncthreads();
  #pragma unroll
  for (int p = 0; p < 2; p++){
    const int nl = p*32 + (t >> 3);
    const int cc = (t & 7) * 8;
    ushort8 ov;
    #pragma unroll
    for (int j = 0; j < 8; j++) ov[j] = tile[nl][cc + j];
    *(ushort8*)(h_t + ((size_t)b*NSP + n0 + nl)*CCH + c0 + cc) = ov;
  }
}

// ------- weight transpose + cast ------------------------------------------------
__global__ __launch_bounds__(256) void transpose_w4_k(const float* __restrict__ w0,
                                                      const float* __restrict__ w1,
                                                      const float* __restrict__ w2,
                                                      const float* __restrict__ w3,
                                                      ushort* __restrict__ wT){
  __shared__ ushort tile[64][72];
  const float* w = (blockIdx.y==0) ? w0 : (blockIdx.y==1) ? w1 : (blockIdx.y==2) ? w2 : w3;
  ushort* dst = wT + (size_t)blockIdx.y * 65536;
  const int tb = blockIdx.x;
  const int r0 = (tb >> 2) * 64, c0 = (tb & 3) * 64;
  const int t = threadIdx.x;
  #pragma unroll
  for (int p = 0; p < 2; p++){
    const int r = p*32 + (t >> 3), cc = (t & 7)*8;
    const float* wr = w + (size_t)(r0 + r)*256 + c0 + cc;
    f32x4 a = *(const f32x4*)wr;
    f32x4 d = *(const f32x4*)(wr + 4);
    #pragma unroll
    for (int j = 0; j < 4; j++){
      tile[r][cc + j]     = f2b(a[j]);
      tile[r][cc + 4 + j] = f2b(d[j]);
    }
  }
  __syncthreads();
  #pragma unroll
  for (int p = 0; p < 2; p++){
    const int r = p*32 + (t >> 3), cc = (t & 7)*8;
    ushort8 ov;
    #pragma unroll
    for (int j = 0; j < 8; j++) ov[j] = tile[cc + j][r];
    *(ushort8*)(dst + (size_t)(c0 + r)*256 + r0 + cc) = ov;
  }
}

// ------------- GEMM: D[m][n] = sum_k A[m][k]*B[n][k]; OutT[n][m] bf16 ----------
__global__ __launch_bounds__(256) void gemm_bt_k(const ushort* __restrict__ A,
                                                 const ushort* __restrict__ B,
                                                 ushort* __restrict__ OutT,
                                                 int M, int N,
                                                 long aStride, long bStride, long oStride,
                                                 const float* __restrict__ biasM,
                                                 const float* __restrict__ biasN){
  const int K = 256;
  const int t = threadIdx.x, w = t >> 6, lane = t & 63;
  const int li = lane & 15, quad = lane >> 4;
  const int m64 = M >> 6;
  const int tm = blockIdx.x % m64, tn = blockIdx.x / m64;
  const int batch = blockIdx.y;
  A    += (size_t)batch * aStride;
  B    += (size_t)batch * bStride;
  OutT += (size_t)batch * oStride;
  const int m0 = tm*64 + w*16;
  const int nb = tn*64;

  short8 afr[8];
  #pragma unroll
  for (int kk = 0; kk < 8; kk++)
    afr[kk] = *(const short8*)(A + (size_t)(m0 + li)*K + kk*32 + quad*8);

  #pragma unroll
  for (int nt = 0; nt < 4; nt++){
    f32x4 acc = {0.f,0.f,0.f,0.f};
    const int n = nb + nt*16 + li;
    short8 bfr[8];
    #pragma unroll
    for (int kk = 0; kk < 8; kk++)           // batch the loads, then MFMA
      bfr[kk] = *(const short8*)(B + (size_t)n*K + kk*32 + quad*8);
    #pragma unroll
    for (int kk = 0; kk < 8; kk++)
      acc = __builtin_amdgcn_mfma_f32_16x16x32_bf16(afr[kk], bfr[kk], acc, 0, 0, 0);
    const float bn = biasN ? biasN[n] : 0.f;
    ushort ov[4];
    #pragma unroll
    for (int r = 0; r < 4; r++){
      const float bm = biasM ? biasM[m0 + quad*4 + r] : 0.f;
      ov[r] = f2b(acc[r] + bm + bn);
    }
    *(uint2*)(OutT + (size_t)n*M + m0 + quad*4) = *(uint2*)ov;
  }
}

// ---------------- flash attention, 2-way key split, K+V in LDS ----------------
// grid 512: bx -> b = bx>>7, qtile = (bx>>1)&63, half = bx&1. 4 waves x 16 q.
__global__ __launch_bounds__(256) void attn_split_k(const ushort* __restrict__ qg,
                                                    const ushort* __restrict__ kg,
                                                    const ushort* __restrict__ vg,
                                                    ushort* __restrict__ Ph,
                                                    float* __restrict__ ml){
  __shared__ __align__(16) ushort Kt[32][264];   // 16896 B
  __shared__ __align__(16) ushort Vt[256][40];   // 20480 B  [c][key], pad 8
  __shared__ __align__(16) ushort Pl[4][16][40]; //  5120 B

  const int t = threadIdx.x, w = t >> 6, lane = t & 63;
  const int li = lane & 15, quad = lane >> 4;
  const int bx = blockIdx.x;
  const int b = bx >> 7, qt = (bx >> 1) & 63, half = bx & 1;
  const int n0 = qt * 64;

  const ushort* kb = kg + (size_t)b*NSP*CCH;
  const ushort* vb = vg + (size_t)b*CCH*NSP;

  short8 qf[8];
  {
    const ushort* qrow = qg + ((size_t)b*NSP + n0 + w*16 + li)*CCH + quad*8;
    #pragma unroll
    for (int kk = 0; kk < 8; kk++) qf[kk] = *(const short8*)(qrow + kk*32);
  }

  f32x4 oacc[16];
  #pragma unroll
  for (int i = 0; i < 16; i++) oacc[i] = (f32x4){0.f,0.f,0.f,0.f};
  float m_i[4] = {-1e30f,-1e30f,-1e30f,-1e30f};
  float l_i[4] = {0.f,0.f,0.f,0.f};
  const float c1 = 0.0625f * 1.44269504088896f;  // C^-0.5 * log2(e)

  for (int it = 0; it < 64; it++){
    const int key0 = half*2048 + it*32;
    __syncthreads();                             // K/V buffers free
    #pragma unroll
    for (int i = 0; i < 4; i++){                 // stage K 32x256
      const int id = t + i*256;
      *(ushort8*)&Kt[id>>5][(id&31)*8] =
        *(const ushort8*)(kb + (size_t)(key0 + (id>>5))*CCH + (id&31)*8);
    }
    #pragma unroll
    for (int i = 0; i < 4; i++){                 // stage V [c][32 keys]
      const int id = t + i*256;
      *(ushort8*)&Vt[id>>2][(id&3)*8] =
        *(const ushort8*)(vb + (size_t)(id>>2)*NSP + key0 + (id&3)*8);
    }
    __syncthreads();                             // staged

    f32x4 sacc[2];
    #pragma unroll
    for (int nt = 0; nt < 2; nt++) sacc[nt] = (f32x4){0.f,0.f,0.f,0.f};
    #pragma unroll
    for (int nt = 0; nt < 2; nt++){
      #pragma unroll
      for (int kk = 0; kk < 8; kk++){
        short8 bfr = *(const short8*)&Kt[nt*16 + li][kk*32 + quad*8];
        sacc[nt] = __builtin_amdgcn_mfma_f32_16x16x32_bf16(qf[kk], bfr, sacc[nt], 0, 0, 0);
      }
    }

    // online softmax
    float rmax[4];
    #pragma unroll
    for (int r = 0; r < 4; r++) rmax[r] = fmaxf(sacc[0][r], sacc[1][r]);
    #pragma unroll
    for (int off = 1; off < 16; off <<= 1){
      #pragma unroll
      for (int r = 0; r < 4; r++) rmax[r] = fmaxf(rmax[r], __shfl_xor(rmax[r], off, 64));
    }
    float alpha[4];
    #pragma unroll
    for (int r = 0; r < 4; r++){
      const float mc = rmax[r] * c1;
      const float mn = fmaxf(m_i[r], mc);
      alpha[r] = __builtin_amdgcn_exp2f(m_i[r] - mn);
      m_i[r] = mn;
    }
    float rsum[4] = {0.f,0.f,0.f,0.f};
    #pragma unroll
    for (int nt = 0; nt < 2; nt++){
      #pragma unroll
      for (int r = 0; r < 4; r++){
        const float pv = __builtin_amdgcn_exp2f(sacc[nt][r]*c1 - m_i[r]);
        rsum[r] += pv;
        Pl[w][quad*4 + r][nt*16 + li] = f2b(pv);
      }
    }
    #pragma unroll
    for (int off = 1; off < 16; off <<= 1){
      #pragma unroll
      for (int r = 0; r < 4; r++) rsum[r] += __shfl_xor(rsum[r], off, 64);
    }
    #pragma unroll
    for (int r = 0; r < 4; r++) l_i[r] = l_i[r]*alpha[r] + rsum[r];
    #pragma unroll
    for (int ct = 0; ct < 16; ct++){
      #pragma unroll
      for (int r = 0; r < 4; r++) oacc[ct][r] *= alpha[r];
    }

    __syncthreads();                             // Pl ordered (same-wave, safety)

    // O += P * V  (A-frag from Pl, B-frag from Vt)
    {
      short8 af = *(const short8*)&Pl[w][li][quad*8];
      #pragma unroll
      for (int ct = 0; ct < 16; ct++){
        short8 vf = *(const short8*)&Vt[ct*16 + li][quad*8];
        oacc[ct] = __builtin_amdgcn_mfma_f32_16x16x32_bf16(af, vf, oacc[ct], 0, 0, 0);
      }
    }
  }

  // write partial O (bf16) + m/l
  const size_t base = ((size_t)(half*BB + b)*NSP + n0 + w*16) * CCH;
  #pragma unroll
  for (int ct = 0; ct < 16; ct++){
    #pragma unroll
    for (int r = 0; r < 4; r++)
      Ph[base + (size_t)(quad*4 + r)*CCH + ct*16 + li] = f2b(oacc[ct][r]);
  }
  if (li == 0){
    #pragma unroll
    for (int r = 0; r < 4; r++){
      float* mlp = ml + ((size_t)(half*BB + b)*NSP + n0 + w*16 + quad*4 + r)*2;
      mlp[0] = m_i[r]; mlp[1] = l_i[r];
    }
  }
}

// ---------------- combine the two key-halves -> Oc bf16 ------------------------
__global__ __launch_bounds__(256) void combine_k(const ushort* __restrict__ Ph,
                                                 const float* __restrict__ ml,
                                                 ushort* __restrict__ Oc){
  const size_t g = (size_t)blockIdx.x*256 + threadIdx.x;   // 524288 threads
  const size_t idx = g >> 5;                // (b*4096+n), 16384 rows
  const int cb = (int)(g & 31) * 8;
  const float m0 = ml[idx*2], l0 = ml[idx*2+1];
  const float m1 = ml[(idx + (size_t)BB*NSP)*2], l1 = ml[(idx + (size_t)BB*NSP)*2+1];
  const float mm = fmaxf(m0, m1);
  const float e0 = __builtin_amdgcn_exp2f(m0 - mm);
  const float e1 = __builtin_amdgcn_exp2f(m1 - mm);
  const float rlt = 1.f / (e0*l0 + e1*l1);
  const float c0 = e0*rlt, c1 = e1*rlt;
  ushort8 p0 = *(const ushort8*)(Ph + idx*CCH + cb);
  ushort8 p1 = *(const ushort8*)(Ph + ((size_t)BB*NSP + idx)*CCH + cb);
  ushort8 o;
  #pragma unroll
  for (int j = 0; j < 8; j++) o[j] = f2b(c0*b2f(p0[j]) + c1*b2f(p1[j]));
  *(ushort8*)(Oc + idx*CCH + cb) = o;
}

// ---------------- final projection + bias + residual (f32 out) -----------------
// D[m=n_spatial][d] = sum_c Oc[n][c]*w3T[d][c]; out[b][d][n] = D + b3[d] + x
__global__ __launch_bounds__(256) void gemm_proj_k(const ushort* __restrict__ A,
                                                   const ushort* __restrict__ Bm,
                                                   const float* __restrict__ b3,
                                                   const float* __restrict__ xin,
                                                   float* __restrict__ out){
  const int K = 256;
  const int t = threadIdx.x, w = t >> 6, lane = t & 63;
  const int li = lane & 15, quad = lane >> 4;
  const int tm = blockIdx.x & 63, tn = blockIdx.x >> 6;   // 64 x 4
  const int batch = blockIdx.y;
  A   += (size_t)batch * NSP * CCH;
  xin += (size_t)batch * CCH * NSP;
  out += (size_t)batch * CCH * NSP;
  const int m0 = tm*64 + w*16;
  const int nb = tn*64;

  short8 afr[8];
  #pragma unroll
  for (int kk = 0; kk < 8; kk++)
    afr[kk] = *(const short8*)(A + (size_t)(m0 + li)*K + kk*32 + quad*8);

  #pragma unroll
  for (int nt = 0; nt < 4; nt++){
    f32x4 acc = {0.f,0.f,0.f,0.f};
    const int d = nb + nt*16 + li;
    short8 bfr[8];
    #pragma unroll
    for (int kk = 0; kk < 8; kk++)
      bfr[kk] = *(const short8*)(Bm + (size_t)d*K + kk*32 + quad*8);
    #pragma unroll
    for (int kk = 0; kk < 8; kk++)
      acc = __builtin_amdgcn_mfma_f32_16x16x32_bf16(afr[kk], bfr[kk], acc, 0, 0, 0);
    const float bias = b3[d];
    const size_t idx = (size_t)d*NSP + m0 + quad*4;
    f32x4 xv = *(const f32x4*)(xin + idx);
    f32x4 ov;
    #pragma unroll
    for (int r = 0; r < 4; r++) ov[r] = acc[r] + bias + xv[r];
    *(f32x4*)(out + idx) = ov;
  }
}

extern "C" void kernel_launch(void* const* d_in, const int* in_sizes, int n_in,
                              void* d_out, int out_size, void* d_ws, size_t ws_size,
                              hipStream_t stream){
  const float* x     = (const float*)d_in[0];
  const float* gamma = (const float*)d_in[1];
  const float* beta  = (const float*)d_in[2];
  const float* w0    = (const float*)d_in[3];
  const float* b0    = (const float*)d_in[4];
  const float* w1    = (const float*)d_in[5];
  const float* b1    = (const float*)d_in[6];
  const float* w2    = (const float*)d_in[7];
  const float* b2    = (const float*)d_in[8];
  const float* w3    = (const float*)d_in[9];
  const float* b3    = (const float*)d_in[10];
  float* out = (float*)d_out;

  const size_t TEN = (size_t)BB * NSP * CCH;      // 4M elements
  ushort* h_t = (ushort*)d_out;                   // d_out[0:8MB], dead after gemms
  ushort* Ph  = (ushort*)d_out;                   // then 2x8MB bf16 partials
  ushort* q_t = (ushort*)d_ws;
  ushort* k_t = q_t + TEN;                        // later reused as Oc
  ushort* v   = k_t + TEN;
  ushort* wT  = v + TEN;                          // 4 x 65536 bf16
  float* stats = (float*)(wT + 4*65536);
  float* ml    = stats + 256;                     // 2*4*4096*2 f32 = 256KB

  transpose_w4_k<<<dim3(16,4), 256, 0, stream>>>(w0, w1, w2, w3, wT);
  gn_stats_k<<<128, 256, 0, stream>>>(x, stats);
  gn_apply_k<<<dim3(64,4,4), 256, 0, stream>>>(x, stats, gamma, beta, h_t);

  const long HS = (long)NSP * CCH;
  gemm_bt_k<<<dim3(256, BB), 256, 0, stream>>>(wT,         h_t, q_t, 256, 4096, 0, HS, HS, b0, nullptr);
  gemm_bt_k<<<dim3(256, BB), 256, 0, stream>>>(wT+65536,   h_t, k_t, 256, 4096, 0, HS, HS, b1, nullptr);
  gemm_bt_k<<<dim3(256, BB), 256, 0, stream>>>(h_t, wT+2*65536, v, 4096, 256, HS, 0, HS, nullptr, b2);

  attn_split_k<<<512, 256, 0, stream>>>(q_t, k_t, v, Ph, ml);

  ushort* Oc = k_t;                               // k_t dead after attn pass
  combine_k<<<2048, 256, 0, stream>>>(Ph, ml, Oc);
  gemm_proj_k<<<dim3(256, BB), 256, 0, stream>>>(Oc, wT + 3*65536, b3, x, out);
}